// Round 7
// baseline (2298.406 us; speedup 1.0000x reference)
//
#include <hip/hip_runtime.h>
#include <math.h>

// Problem dims
#define MR 16384      // B*T rows
#define TT 1024
#define BB 16
#define DI_ 800
#define HH 400
#define LDBC 160      // padded dbc row: dt@0..24, B@32..95, C@96..159
#define LOG2E 1.44269504088896f

typedef short s16x8 __attribute__((ext_vector_type(8)));
typedef unsigned short u16x8 __attribute__((ext_vector_type(8)));
typedef float f32x4 __attribute__((ext_vector_type(4)));

__device__ __forceinline__ float sigf(float x) { return 1.f / (1.f + __expf(-x)); }

__device__ __forceinline__ unsigned short f2bf(float f) {
  unsigned int u = __builtin_bit_cast(unsigned int, f);
  u = (u + 0x7fffu + ((u >> 16) & 1u)) >> 16;   // RNE
  return (unsigned short)u;
}

__device__ __forceinline__ float waveSum(float v) {
  #pragma unroll
  for (int off = 32; off; off >>= 1) v += __shfl_xor(v, off);
  return v;
}

// ---------------------------------------------------------------------------
// Weight transpose+convert: W[K][N] f32 -> Wt[Npad][Kt] bf16, zero padded.
// ---------------------------------------------------------------------------
__global__ __launch_bounds__(256) void wtrans(
    const float* __restrict__ W, int K, int N,
    unsigned short* __restrict__ Wt, int Kt, int Npad)
{
  __shared__ float t[32][33];
  const int k0 = blockIdx.x * 32, n0 = blockIdx.y * 32;
  const int tx = threadIdx.x & 31, ty = threadIdx.x >> 5;
  #pragma unroll
  for (int r = ty; r < 32; r += 8) {
    int k = k0 + r, n = n0 + tx;
    t[r][tx] = (k < K && n < N) ? W[(long)k * N + n] : 0.f;
  }
  __syncthreads();
  #pragma unroll
  for (int r = ty; r < 32; r += 8) {
    int n = n0 + r, k = k0 + tx;
    if (n < Npad && k < Kt) Wt[(long)n * Kt + k] = f2bf(t[tx][r]);
  }
}

// ---------------------------------------------------------------------------
// MFMA GEMM: C[M,N] = act(A[M,K]f32 @ Wt^T + bias), A converted bf16 at stage.
// BM=128 BN=64 BK=32, 4 waves (2x2), mfma_f32_16x16x32_bf16.
// ACT: 0=none 1=relu 2=sigmoid*e1 4=FiLM(e1*e2+v).
// remap: dbc column padding, n -> n + (n>=25 ? 7 : 0)  [B,C contiguous]
// ---------------------------------------------------------------------------
#define LDS_S 40   // padded LDS row stride (elems) for 32-elem rows

template <int ACT>
__global__ __launch_bounds__(256) void mgemm(
    const float* __restrict__ A, int lda,
    const unsigned short* __restrict__ Wt, int Kt,
    const float* __restrict__ bias,
    float* __restrict__ C, int ldc,
    const float* __restrict__ e1, int lde1,
    const float* __restrict__ e2, int lde2,
    int N, int K, int remap)
{
  __shared__ unsigned short As[128 * LDS_S];
  __shared__ unsigned short Bs[64 * LDS_S];
  const int tid = threadIdx.x;
  const int wave = tid >> 6, lane = tid & 63;
  const int wr = wave >> 1, wc = wave & 1;
  const int m0 = blockIdx.y * 128, n0 = blockIdx.x * 64;

  const int ar = tid >> 1, akc = (tid & 1) * 16;   // A stage: row, k-offset
  const int bn = tid >> 2, bkc = (tid & 3) * 8;    // B stage: n-row, k-offset
  const int li = lane & 15, lk = (lane >> 4) * 8;  // fragment indices

  f32x4 acc[4][2];
  #pragma unroll
  for (int i = 0; i < 4; ++i)
    #pragma unroll
    for (int j = 0; j < 2; ++j) acc[i][j] = (f32x4){0.f, 0.f, 0.f, 0.f};

  for (int k0 = 0; k0 < Kt; k0 += 32) {
    // stage A (f32 -> bf16), row m0+ar, cols k0+akc .. +15
    {
      const float* src = A + (long)(m0 + ar) * lda + k0 + akc;
      unsigned short tmp[16];
      #pragma unroll
      for (int j = 0; j < 16; j += 4) {
        int k = k0 + akc + j;
        float x0, x1, x2, x3;
        if (k + 3 < K) { float4 v = *(const float4*)(src + j); x0 = v.x; x1 = v.y; x2 = v.z; x3 = v.w; }
        else {
          x0 = (k < K) ? src[j] : 0.f;     x1 = (k + 1 < K) ? src[j + 1] : 0.f;
          x2 = (k + 2 < K) ? src[j + 2] : 0.f; x3 = (k + 3 < K) ? src[j + 3] : 0.f;
        }
        tmp[j] = f2bf(x0); tmp[j + 1] = f2bf(x1); tmp[j + 2] = f2bf(x2); tmp[j + 3] = f2bf(x3);
      }
      #pragma unroll
      for (int j = 0; j < 16; j += 8)
        *(u16x8*)&As[ar * LDS_S + akc + j] = *(u16x8*)&tmp[j];
    }
    // stage B (already bf16, zero-padded -> unguarded)
    {
      const unsigned short* src = Wt + (long)(n0 + bn) * Kt + k0 + bkc;
      *(u16x8*)&Bs[bn * LDS_S + bkc] = *(const u16x8*)src;
    }
    __syncthreads();
    s16x8 bfrag0 = *(const s16x8*)&Bs[(wc * 32 + li) * LDS_S + lk];
    s16x8 bfrag1 = *(const s16x8*)&Bs[(wc * 32 + 16 + li) * LDS_S + lk];
    #pragma unroll
    for (int mi = 0; mi < 4; ++mi) {
      s16x8 afrag = *(const s16x8*)&As[(wr * 64 + mi * 16 + li) * LDS_S + lk];
      acc[mi][0] = __builtin_amdgcn_mfma_f32_16x16x32_bf16(afrag, bfrag0, acc[mi][0], 0, 0, 0);
      acc[mi][1] = __builtin_amdgcn_mfma_f32_16x16x32_bf16(afrag, bfrag1, acc[mi][1], 0, 0, 0);
    }
    __syncthreads();
  }

  // epilogue: D col = lane&15, row = 4*(lane>>4)+reg
  const int di4 = (lane >> 4) * 4;
  #pragma unroll
  for (int mi = 0; mi < 4; ++mi) {
    #pragma unroll
    for (int nj = 0; nj < 2; ++nj) {
      int n = n0 + wc * 32 + nj * 16 + li;
      if (n < N) {
        #pragma unroll
        for (int reg = 0; reg < 4; ++reg) {
          long r = m0 + wr * 64 + mi * 16 + di4 + reg;
          float v = acc[mi][nj][reg];
          if (bias) v += bias[n];
          float o;
          if (ACT == 0)      o = v;
          else if (ACT == 1) o = fmaxf(v, 0.f);
          else if (ACT == 2) o = sigf(v) * e1[r * lde1 + n];
          else               o = fmaf(e1[r * lde1 + n], e2[r * lde2 + n], v);
          int nn = remap ? (n + (n >= 25 ? 7 : 0)) : n;
          C[r * ldc + nn] = o;
        }
      }
    }
  }
}

// ---------------------------------------------------------------------------
// fp32 SGEMM (kept only for the K=25 delta GEMM). ACT 3 = softplus.
// ---------------------------------------------------------------------------
template <int ACT>
__global__ __launch_bounds__(256) void gemm_kernel(
    const float* __restrict__ A, int lda,
    const float* __restrict__ W, int ldw,
    const float* __restrict__ bias,
    float* __restrict__ C, int ldc,
    int N, int K)
{
  __shared__ float As[16][68];
  __shared__ float Bs[16][68];
  const int tid = threadIdx.x;
  const int tx = tid & 15;
  const int ty = tid >> 4;
  const int m0 = blockIdx.y * 64, n0 = blockIdx.x * 64;
  const int lm  = tid >> 2;
  const int lk4 = (tid & 3) * 4;
  const int wn  = tid & 63;
  const int wk4 = (tid >> 6) * 4;

  float acc[4][4] = {};

  for (int k0 = 0; k0 < K; k0 += 16) {
    #pragma unroll
    for (int i = 0; i < 4; ++i) {
      int k = k0 + lk4 + i;
      As[lk4 + i][lm] = (k < K) ? A[(long)(m0 + lm) * lda + k] : 0.f;
    }
    #pragma unroll
    for (int i = 0; i < 4; ++i) {
      int k = k0 + wk4 + i;
      int n = n0 + wn;
      Bs[wk4 + i][wn] = (k < K && n < N) ? W[(long)k * ldw + n] : 0.f;
    }
    __syncthreads();
    #pragma unroll
    for (int kk = 0; kk < 16; ++kk) {
      float4 av = *(const float4*)&As[kk][ty * 4];
      float a[4] = {av.x, av.y, av.z, av.w};
      float b[4] = {Bs[kk][tx], Bs[kk][tx + 16], Bs[kk][tx + 32], Bs[kk][tx + 48]};
      #pragma unroll
      for (int i = 0; i < 4; ++i)
        #pragma unroll
        for (int j = 0; j < 4; ++j)
          acc[i][j] = fmaf(a[i], b[j], acc[i][j]);
    }
    __syncthreads();
  }

  #pragma unroll
  for (int i = 0; i < 4; ++i) {
    long r = m0 + ty * 4 + i;
    #pragma unroll
    for (int j = 0; j < 4; ++j) {
      int n = n0 + tx + 16 * j;
      if (n < N) {
        float v = acc[i][j];
        if (bias) v += bias[n];
        float o;
        if (ACT == 3) o = (v > 20.f) ? v : __logf(1.f + __expf(v));
        else          o = v;
        C[r * ldc + n] = o;
      }
    }
  }
}

// ---------------------------------------------------------------------------
// Depthwise causal conv (DC=4) + SiLU.
// ---------------------------------------------------------------------------
__global__ __launch_bounds__(256) void conv_kernel(
    const float* __restrict__ xz, const float* __restrict__ cw,
    const float* __restrict__ cb, float* __restrict__ xs)
{
  long gid = (long)blockIdx.x * 256 + threadIdx.x;
  if (gid >= (long)MR * DI_) return;
  int c = (int)(gid % DI_);
  long r = gid / DI_;
  int t = (int)(r & (TT - 1));
  float acc = cb[c];
  #pragma unroll
  for (int k = 0; k < 4; ++k) {
    int tt = t + k - 3;
    if (tt >= 0) acc = fmaf(cw[c * 4 + k], xz[(r + k - 3) * 1600 + c], acc);
  }
  xs[gid] = acc * sigf(acc);
}

// ---------------------------------------------------------------------------
// Selective scan v3: 4 channels/wave, 16 lanes/channel, 4 states/lane.
// 3200 waves. Pointer-bump addressing, named register ring (no struct copies),
// 4-step unrolled groups, consume-then-prefetch. No LDS, no barriers.
// y = (scan_y + D*u) * silu(z) -> yout (stride 1600, dead xc cols of xz)
// ---------------------------------------------------------------------------
__global__ __launch_bounds__(256) void scan_kernel(
    const float* __restrict__ delta,   // [M,800]
    const float* __restrict__ dbc,     // [M,160] padded
    const float* __restrict__ xz,      // [M,1600]; z at +800
    const float* __restrict__ A_log,   // [800,64]
    const float* __restrict__ Dp,      // [800]
    const float* __restrict__ xs,      // [M,800] conv output u
    float* __restrict__ yout)          // [M,1600] strided; y at cols 0..799
{
  const int wid = blockIdx.x * 4 + (threadIdx.x >> 6);   // 0..3199
  const int lane = threadIdx.x & 63;
  const int b = wid / 200, cg = wid % 200;               // 200 waves/batch
  const int cl = lane >> 4, sq = lane & 15;              // channel-in-wave, state-quad
  const int c = cg * 4 + cl;
  const long rowbase = (long)b * TT;

  float a2[4], h[4] = {0.f, 0.f, 0.f, 0.f};
  {
    float4 al = *(const float4*)&A_log[c * 64 + sq * 4];
    a2[0] = -__expf(al.x) * LOG2E; a2[1] = -__expf(al.y) * LOG2E;
    a2[2] = -__expf(al.z) * LOG2E; a2[3] = -__expf(al.w) * LOG2E;
  }
  const float dcoef = Dp[c];

  const float* pB = dbc + rowbase * LDBC + 32 + sq * 4;
  const float* pC = dbc + rowbase * LDBC + 96 + sq * 4;
  const float* pD = delta + rowbase * DI_ + c;
  const float* pU = xs + rowbase * DI_ + c;
  const float* pZ = xz + rowbase * 1600 + 800 + c;
  float* pY = yout + rowbase * 1600 + c;

  float4 rB[4], rC[4];
  float rD[4], rU[4], rZ[4];
  #pragma unroll
  for (int s = 0; s < 4; ++s) {
    rB[s] = *(const float4*)(pB + s * LDBC);
    rC[s] = *(const float4*)(pC + s * LDBC);
    rD[s] = pD[s * DI_];
    rU[s] = pU[s * DI_];
    rZ[s] = pZ[s * 1600];
  }
  pB += 4 * LDBC; pC += 4 * LDBC; pD += 4 * DI_; pU += 4 * DI_; pZ += 4 * 1600;

  #define SCAN_STEP(s, PREFETCH)                                              \
    {                                                                         \
      const float dl = rD[s], u = rU[s], zz = rZ[s];                          \
      const float4 B4 = rB[s], C4 = rC[s];                                    \
      if (PREFETCH) {                                                         \
        rB[s] = *(const float4*)(pB + (s) * LDBC);                            \
        rC[s] = *(const float4*)(pC + (s) * LDBC);                            \
        rD[s] = pD[(s) * DI_];                                                \
        rU[s] = pU[(s) * DI_];                                                \
        rZ[s] = pZ[(s) * 1600];                                               \
      }                                                                       \
      const float du = dl * u;                                                \
      float y = 0.f, dA;                                                      \
      dA = exp2f(dl * a2[0]); h[0] = fmaf(dA, h[0], du * B4.x); y = fmaf(h[0], C4.x, y); \
      dA = exp2f(dl * a2[1]); h[1] = fmaf(dA, h[1], du * B4.y); y = fmaf(h[1], C4.y, y); \
      dA = exp2f(dl * a2[2]); h[2] = fmaf(dA, h[2], du * B4.z); y = fmaf(h[2], C4.z, y); \
      dA = exp2f(dl * a2[3]); h[3] = fmaf(dA, h[3], du * B4.w); y = fmaf(h[3], C4.w, y); \
      y += __shfl_xor(y, 1); y += __shfl_xor(y, 2);                           \
      y += __shfl_xor(y, 4); y += __shfl_xor(y, 8);                           \
      if (sq == 0) pY[(s) * 1600] = (y + dcoef * u) * (zz * sigf(zz));        \
    }

  for (int g = 0; g < TT / 4 - 1; ++g) {
    SCAN_STEP(0, 1) SCAN_STEP(1, 1) SCAN_STEP(2, 1) SCAN_STEP(3, 1)
    pB += 4 * LDBC; pC += 4 * LDBC; pD += 4 * DI_; pU += 4 * DI_;
    pZ += 4 * 1600; pY += 4 * 1600;
  }
  SCAN_STEP(0, 0) SCAN_STEP(1, 0) SCAN_STEP(2, 0) SCAN_STEP(3, 0)
  #undef SCAN_STEP
}

// ---------------------------------------------------------------------------
// Fused double LayerNorm: out = LN2( LN1(x+m) + skip ), row width 400
// ---------------------------------------------------------------------------
__global__ __launch_bounds__(64) void ln2_kernel(
    const float* __restrict__ x, const float* __restrict__ m,
    const float* __restrict__ skip,
    const float* __restrict__ g1, const float* __restrict__ b1,
    const float* __restrict__ g2, const float* __restrict__ b2,
    float* __restrict__ out)
{
  const long row = blockIdx.x;
  const int lane = threadIdx.x;
  float v[7];
  float s = 0.f;
  #pragma unroll
  for (int i = 0; i < 7; ++i) {
    int cx = lane + i * 64;
    if (cx < HH) { v[i] = x[row * HH + cx] + m[row * HH + cx]; s += v[i]; }
    else v[i] = 0.f;
  }
  s = waveSum(s);
  float mu = s * (1.f / HH);
  float s2 = 0.f;
  #pragma unroll
  for (int i = 0; i < 7; ++i) {
    int cx = lane + i * 64;
    if (cx < HH) { float d = v[i] - mu; s2 += d * d; }
  }
  s2 = waveSum(s2);
  float rstd = rsqrtf(s2 * (1.f / HH) + 1e-5f);

  s = 0.f;
  #pragma unroll
  for (int i = 0; i < 7; ++i) {
    int cx = lane + i * 64;
    if (cx < HH) {
      v[i] = fmaf(g1[cx], (v[i] - mu) * rstd, b1[cx]) + skip[row * HH + cx];
      s += v[i];
    }
  }
  s = waveSum(s);
  float mu2 = s * (1.f / HH);
  s2 = 0.f;
  #pragma unroll
  for (int i = 0; i < 7; ++i) {
    int cx = lane + i * 64;
    if (cx < HH) { float d = v[i] - mu2; s2 += d * d; }
  }
  s2 = waveSum(s2);
  float rstd2 = rsqrtf(s2 * (1.f / HH) + 1e-5f);
  #pragma unroll
  for (int i = 0; i < 7; ++i) {
    int cx = lane + i * 64;
    if (cx < HH) out[row * HH + cx] = fmaf(g2[cx], (v[i] - mu2) * rstd2, b2[cx]);
  }
}

// ---------------------------------------------------------------------------
extern "C" void kernel_launch(void* const* d_in, const int* in_sizes, int n_in,
                              void* d_out, int out_size, void* d_ws, size_t ws_size,
                              hipStream_t stream) {
  const float* mag   = (const float*)d_in[0];
  const float* audio = (const float*)d_in[1];
  const float* video = (const float*)d_in[2];
  const float* apw = (const float*)d_in[3];
  const float* apb = (const float*)d_in[4];
  const float* vpw = (const float*)d_in[5];
  const float* vpb = (const float*)d_in[6];
  const float* fgw = (const float*)d_in[7];
  const float* fgb = (const float*)d_in[8];
  const float* fbw = (const float*)d_in[9];
  const float* fbb = (const float*)d_in[10];
  const float* ipw = (const float*)d_in[11];
  const float* cw  = (const float*)d_in[12];
  const float* cb  = (const float*)d_in[13];
  const float* xpw = (const float*)d_in[14];
  const float* dtw = (const float*)d_in[15];
  const float* dtb = (const float*)d_in[16];
  const float* alog= (const float*)d_in[17];
  const float* dd  = (const float*)d_in[18];
  const float* opw = (const float*)d_in[19];
  const float* mng = (const float*)d_in[20];
  const float* mnb = (const float*)d_in[21];
  const float* spw = (const float*)d_in[22];
  const float* spb = (const float*)d_in[23];
  const float* fng = (const float*)d_in[24];
  const float* fnb = (const float*)d_in[25];
  const float* fc1w= (const float*)d_in[26];
  const float* fc1b= (const float*)d_in[27];
  const float* fc2w= (const float*)d_in[28];
  const float* fc2b= (const float*)d_in[29];
  const float* fc3w= (const float*)d_in[30];
  const float* fc3b= (const float*)d_in[31];
  const float* mmw = (const float*)d_in[32];
  const float* mmb = (const float*)d_in[33];
  float* outp = (float*)d_out;

  float* w = (float*)d_ws;
  const long M = MR;
  float* av   = w;              // [M,400] audio_vec; later m
  float* vv   = w + M * 400;    // [M,400] video_vec
  float* gam  = w + M * 800;    // [M,400] gamma (dead after FiLM)
  float* dbcb = w + M * 800;    // [M,160] padded dbc (reuses gam)
  float* xbuf = w + M * 1200;   // [M,400] x
  float* skip = w + M * 1600;   // [M,400]
  float* xzb  = w + M * 2000;   // [M,1600] xz; y into cols 0..799; later h1,h2
  float* h1   = w + M * 2000;   // [M,600]
  float* h2   = w + M * 2600;   // [M,600]
  float* xsb  = w + M * 3600;   // [M,800] conv u; later mout
  float* mout = w + M * 3600;   // [M,400]
  float* delt = w + M * 4400;   // [M,800] delta; later h3
  float* h3   = w + M * 4400;   // [M,600]
  unsigned short* wt = (unsigned short*)(w + M * 5200);  // bf16 weights arena
  // high-water ~350.6 MB

  // transposed bf16 weights: [Npad][Kt]
  unsigned short* apT = wt;                 // 448 x 2080
  unsigned short* spT = apT + 448 * 2080;
  unsigned short* vpT = spT + 448 * 2080;   // 448 x 512
  unsigned short* fgT = vpT + 448 * 512;    // 448 x 416
  unsigned short* fbT = fgT + 448 * 416;
  unsigned short* ipT = fbT + 448 * 416;    // 1600 x 416
  unsigned short* xpT = ipT + 1600 * 416;   // 192 x 800
  unsigned short* opT = xpT + 192 * 800;    // 448 x 800
  unsigned short* f1T = opT + 448 * 800;    // 640 x 416
  unsigned short* f2T = f1T + 640 * 416;    // 640 x 608
  unsigned short* f3T = f2T + 640 * 608;
  unsigned short* mmT = f3T + 640 * 608;    // 320 x 608

  const dim3 blk(256);

  // weight transposes (bf16, zero-padded)
  wtrans<<<dim3(65, 14), blk, 0, stream>>>(apw, 2056, 400, apT, 2080, 448);
  wtrans<<<dim3(65, 14), blk, 0, stream>>>(spw, 2056, 400, spT, 2080, 448);
  wtrans<<<dim3(16, 14), blk, 0, stream>>>(vpw, 512, 400, vpT, 512, 448);
  wtrans<<<dim3(13, 14), blk, 0, stream>>>(fgw, 400, 400, fgT, 416, 448);
  wtrans<<<dim3(13, 14), blk, 0, stream>>>(fbw, 400, 400, fbT, 416, 448);
  wtrans<<<dim3(13, 50), blk, 0, stream>>>(ipw, 400, 1600, ipT, 416, 1600);
  wtrans<<<dim3(25, 6),  blk, 0, stream>>>(xpw, 800, 153, xpT, 800, 192);
  wtrans<<<dim3(25, 14), blk, 0, stream>>>(opw, 800, 400, opT, 800, 448);
  wtrans<<<dim3(13, 20), blk, 0, stream>>>(fc1w, 400, 600, f1T, 416, 640);
  wtrans<<<dim3(19, 20), blk, 0, stream>>>(fc2w, 600, 600, f2T, 608, 640);
  wtrans<<<dim3(19, 20), blk, 0, stream>>>(fc3w, 600, 600, f3T, 608, 640);
  wtrans<<<dim3(19, 10), blk, 0, stream>>>(mmw, 600, 257, mmT, 608, 320);

  const int gy = MR / 128;  // 128

  // audio_vec / video_vec / skip
  mgemm<0><<<dim3(7, gy), blk, 0, stream>>>(audio, 2056, apT, 2080, apb, av, 400, nullptr, 0, nullptr, 0, 400, 2056, 0);
  mgemm<0><<<dim3(7, gy), blk, 0, stream>>>(video, 512, vpT, 512, vpb, vv, 400, nullptr, 0, nullptr, 0, 400, 512, 0);
  mgemm<0><<<dim3(7, gy), blk, 0, stream>>>(audio, 2056, spT, 2080, spb, skip, 400, nullptr, 0, nullptr, 0, 400, 2056, 0);
  // gamma; then x = av*gamma + (beta + bias)
  mgemm<0><<<dim3(7, gy), blk, 0, stream>>>(vv, 400, fgT, 416, fgb, gam, 400, nullptr, 0, nullptr, 0, 400, 400, 0);
  mgemm<4><<<dim3(7, gy), blk, 0, stream>>>(vv, 400, fbT, 416, fbb, xbuf, 400, av, 400, gam, 400, 400, 400, 0);
  // xz = x @ in_proj_w
  mgemm<0><<<dim3(25, gy), blk, 0, stream>>>(xbuf, 400, ipT, 416, nullptr, xzb, 1600, nullptr, 0, nullptr, 0, 1600, 400, 0);
  // conv + silu -> xs
  conv_kernel<<<dim3((MR * DI_) / 256), blk, 0, stream>>>(xzb, cw, cb, xsb);
  // dbc = xs @ x_proj_w  (padded/remapped into ld=160)
  mgemm<0><<<dim3(3, gy), blk, 0, stream>>>(xsb, 800, xpT, 800, nullptr, dbcb, LDBC, nullptr, 0, nullptr, 0, 153, 800, 1);
  // delta = softplus(dt @ dt_proj_w + b)  [fp32, K=25]
  gemm_kernel<3><<<dim3(13, MR / 64), blk, 0, stream>>>(dbcb, LDBC, dtw, 800, dtb, delt, 800, 800, 25);
  // selective scan -> y into xzb cols 0..799 (stride 1600)
  scan_kernel<<<dim3(800), blk, 0, stream>>>(delt, dbcb, xzb, alog, dd, xsb, xzb);
  // m = y @ out_proj_w -> av
  mgemm<0><<<dim3(7, gy), blk, 0, stream>>>(xzb, 1600, opT, 800, nullptr, av, 400, nullptr, 0, nullptr, 0, 400, 800, 0);
  // mamba_out = LN2(LN1(x+m)+skip) -> mout
  ln2_kernel<<<dim3(MR), dim3(64), 0, stream>>>(xbuf, av, skip, mng, mnb, fng, fnb, mout);
  // MLP
  mgemm<1><<<dim3(10, gy), blk, 0, stream>>>(mout, 400, f1T, 416, fc1b, h1, 600, nullptr, 0, nullptr, 0, 600, 400, 0);
  mgemm<1><<<dim3(10, gy), blk, 0, stream>>>(h1, 600, f2T, 608, fc2b, h2, 600, nullptr, 0, nullptr, 0, 600, 600, 0);
  mgemm<1><<<dim3(10, gy), blk, 0, stream>>>(h2, 600, f3T, 608, fc3b, h3, 600, nullptr, 0, nullptr, 0, 600, 600, 0);
  // mask = sigmoid(h3 @ mmw + b) * mag -> out
  mgemm<2><<<dim3(5, gy), blk, 0, stream>>>(h3, 600, mmT, 608, mmb, outp, 257, mag, 257, nullptr, 0, 257, 600, 0);
}

// Round 10
// 2152.718 us; speedup vs baseline: 1.0677x; 1.0677x over previous
//
#include <hip/hip_runtime.h>
#include <math.h>

// Problem dims
#define MR 16384      // B*T rows
#define TT 1024
#define BB 16
#define DI_ 800
#define HH 400
#define LDBC 160      // padded dbc row: dt@0..24, B@32..95, C@96..159
#define LOG2E 1.44269504088896f

typedef short s16x8 __attribute__((ext_vector_type(8)));
typedef unsigned short u16x8 __attribute__((ext_vector_type(8)));
typedef float f32x4 __attribute__((ext_vector_type(4)));

__device__ __forceinline__ float fexp2(float x) { return __builtin_amdgcn_exp2f(x); }
__device__ __forceinline__ float sigf(float x) { return 1.f / (1.f + __expf(-x)); }
// fast sigmoid via raw v_exp_f32: 1/(1+2^(-x*log2e))
__device__ __forceinline__ float sigfast(float x) {
  return __builtin_amdgcn_rcpf(1.f + fexp2(-x * LOG2E));
}

__device__ __forceinline__ unsigned short f2bf(float f) {
  unsigned int u = __builtin_bit_cast(unsigned int, f);
  u = (u + 0x7fffu + ((u >> 16) & 1u)) >> 16;   // RNE
  return (unsigned short)u;
}

__device__ __forceinline__ float waveSum(float v) {
  #pragma unroll
  for (int off = 32; off; off >>= 1) v += __shfl_xor(v, off);
  return v;
}

// ---------------------------------------------------------------------------
// Weight transpose+convert: W[K][N] f32 -> Wt[Npad][Kt] bf16, zero padded.
// ---------------------------------------------------------------------------
__global__ __launch_bounds__(256) void wtrans(
    const float* __restrict__ W, int K, int N,
    unsigned short* __restrict__ Wt, int Kt, int Npad)
{
  __shared__ float t[32][33];
  const int k0 = blockIdx.x * 32, n0 = blockIdx.y * 32;
  const int tx = threadIdx.x & 31, ty = threadIdx.x >> 5;
  #pragma unroll
  for (int r = ty; r < 32; r += 8) {
    int k = k0 + r, n = n0 + tx;
    t[r][tx] = (k < K && n < N) ? W[(long)k * N + n] : 0.f;
  }
  __syncthreads();
  #pragma unroll
  for (int r = ty; r < 32; r += 8) {
    int n = n0 + r, k = k0 + tx;
    if (n < Npad && k < Kt) Wt[(long)n * Kt + k] = f2bf(t[tx][r]);
  }
}

// ---------------------------------------------------------------------------
// MFMA GEMM: C[M,N] = act(A[M,K]f32 @ Wt^T + bias), A converted bf16 at stage.
// BM=128 BN=64 BK=32, 4 waves (2x2), mfma_f32_16x16x32_bf16.
// ACT: 0=none 1=relu 2=sigmoid*e1 4=FiLM(e1*e2+v).
// remap: dbc column padding, n -> n + (n>=25 ? 7 : 0)  [B,C contiguous]
// ---------------------------------------------------------------------------
#define LDS_S 40   // padded LDS row stride (elems) for 32-elem rows

template <int ACT>
__global__ __launch_bounds__(256) void mgemm(
    const float* __restrict__ A, int lda,
    const unsigned short* __restrict__ Wt, int Kt,
    const float* __restrict__ bias,
    float* __restrict__ C, int ldc,
    const float* __restrict__ e1, int lde1,
    const float* __restrict__ e2, int lde2,
    int N, int K, int remap)
{
  __shared__ unsigned short As[128 * LDS_S];
  __shared__ unsigned short Bs[64 * LDS_S];
  const int tid = threadIdx.x;
  const int wave = tid >> 6, lane = tid & 63;
  const int wr = wave >> 1, wc = wave & 1;
  const int m0 = blockIdx.y * 128, n0 = blockIdx.x * 64;

  const int ar = tid >> 1, akc = (tid & 1) * 16;   // A stage: row, k-offset
  const int bn = tid >> 2, bkc = (tid & 3) * 8;    // B stage: n-row, k-offset
  const int li = lane & 15, lk = (lane >> 4) * 8;  // fragment indices

  f32x4 acc[4][2];
  #pragma unroll
  for (int i = 0; i < 4; ++i)
    #pragma unroll
    for (int j = 0; j < 2; ++j) acc[i][j] = (f32x4){0.f, 0.f, 0.f, 0.f};

  for (int k0 = 0; k0 < Kt; k0 += 32) {
    // stage A (f32 -> bf16), row m0+ar, cols k0+akc .. +15
    {
      const float* src = A + (long)(m0 + ar) * lda + k0 + akc;
      unsigned short tmp[16];
      #pragma unroll
      for (int j = 0; j < 16; j += 4) {
        int k = k0 + akc + j;
        float x0, x1, x2, x3;
        if (k + 3 < K) { float4 v = *(const float4*)(src + j); x0 = v.x; x1 = v.y; x2 = v.z; x3 = v.w; }
        else {
          x0 = (k < K) ? src[j] : 0.f;     x1 = (k + 1 < K) ? src[j + 1] : 0.f;
          x2 = (k + 2 < K) ? src[j + 2] : 0.f; x3 = (k + 3 < K) ? src[j + 3] : 0.f;
        }
        tmp[j] = f2bf(x0); tmp[j + 1] = f2bf(x1); tmp[j + 2] = f2bf(x2); tmp[j + 3] = f2bf(x3);
      }
      #pragma unroll
      for (int j = 0; j < 16; j += 8)
        *(u16x8*)&As[ar * LDS_S + akc + j] = *(u16x8*)&tmp[j];
    }
    // stage B (already bf16, zero-padded -> unguarded)
    {
      const unsigned short* src = Wt + (long)(n0 + bn) * Kt + k0 + bkc;
      *(u16x8*)&Bs[bn * LDS_S + bkc] = *(const u16x8*)src;
    }
    __syncthreads();
    s16x8 bfrag0 = *(const s16x8*)&Bs[(wc * 32 + li) * LDS_S + lk];
    s16x8 bfrag1 = *(const s16x8*)&Bs[(wc * 32 + 16 + li) * LDS_S + lk];
    #pragma unroll
    for (int mi = 0; mi < 4; ++mi) {
      s16x8 afrag = *(const s16x8*)&As[(wr * 64 + mi * 16 + li) * LDS_S + lk];
      acc[mi][0] = __builtin_amdgcn_mfma_f32_16x16x32_bf16(afrag, bfrag0, acc[mi][0], 0, 0, 0);
      acc[mi][1] = __builtin_amdgcn_mfma_f32_16x16x32_bf16(afrag, bfrag1, acc[mi][1], 0, 0, 0);
    }
    __syncthreads();
  }

  // epilogue: D col = lane&15, row = 4*(lane>>4)+reg
  const int di4 = (lane >> 4) * 4;
  #pragma unroll
  for (int mi = 0; mi < 4; ++mi) {
    #pragma unroll
    for (int nj = 0; nj < 2; ++nj) {
      int n = n0 + wc * 32 + nj * 16 + li;
      if (n < N) {
        #pragma unroll
        for (int reg = 0; reg < 4; ++reg) {
          long r = m0 + wr * 64 + mi * 16 + di4 + reg;
          float v = acc[mi][nj][reg];
          if (bias) v += bias[n];
          float o;
          if (ACT == 0)      o = v;
          else if (ACT == 1) o = fmaxf(v, 0.f);
          else if (ACT == 2) o = sigf(v) * e1[r * lde1 + n];
          else               o = fmaf(e1[r * lde1 + n], e2[r * lde2 + n], v);
          int nn = remap ? (n + (n >= 25 ? 7 : 0)) : n;
          C[r * ldc + nn] = o;
        }
      }
    }
  }
}

// ---------------------------------------------------------------------------
// fp32 SGEMM (kept only for the K=25 delta GEMM). ACT 3 = softplus.
// ---------------------------------------------------------------------------
template <int ACT>
__global__ __launch_bounds__(256) void gemm_kernel(
    const float* __restrict__ A, int lda,
    const float* __restrict__ W, int ldw,
    const float* __restrict__ bias,
    float* __restrict__ C, int ldc,
    int N, int K)
{
  __shared__ float As[16][68];
  __shared__ float Bs[16][68];
  const int tid = threadIdx.x;
  const int tx = tid & 15;
  const int ty = tid >> 4;
  const int m0 = blockIdx.y * 64, n0 = blockIdx.x * 64;
  const int lm  = tid >> 2;
  const int lk4 = (tid & 3) * 4;
  const int wn  = tid & 63;
  const int wk4 = (tid >> 6) * 4;

  float acc[4][4] = {};

  for (int k0 = 0; k0 < K; k0 += 16) {
    #pragma unroll
    for (int i = 0; i < 4; ++i) {
      int k = k0 + lk4 + i;
      As[lk4 + i][lm] = (k < K) ? A[(long)(m0 + lm) * lda + k] : 0.f;
    }
    #pragma unroll
    for (int i = 0; i < 4; ++i) {
      int k = k0 + wk4 + i;
      int n = n0 + wn;
      Bs[wk4 + i][wn] = (k < K && n < N) ? W[(long)k * ldw + n] : 0.f;
    }
    __syncthreads();
    #pragma unroll
    for (int kk = 0; kk < 16; ++kk) {
      float4 av = *(const float4*)&As[kk][ty * 4];
      float a[4] = {av.x, av.y, av.z, av.w};
      float b[4] = {Bs[kk][tx], Bs[kk][tx + 16], Bs[kk][tx + 32], Bs[kk][tx + 48]};
      #pragma unroll
      for (int i = 0; i < 4; ++i)
        #pragma unroll
        for (int j = 0; j < 4; ++j)
          acc[i][j] = fmaf(a[i], b[j], acc[i][j]);
    }
    __syncthreads();
  }

  #pragma unroll
  for (int i = 0; i < 4; ++i) {
    long r = m0 + ty * 4 + i;
    #pragma unroll
    for (int j = 0; j < 4; ++j) {
      int n = n0 + tx + 16 * j;
      if (n < N) {
        float v = acc[i][j];
        if (bias) v += bias[n];
        float o;
        if (ACT == 3) o = (v > 20.f) ? v : __logf(1.f + __expf(v));
        else          o = v;
        C[r * ldc + n] = o;
      }
    }
  }
}

// ---------------------------------------------------------------------------
// Depthwise causal conv (DC=4) + SiLU.
// ---------------------------------------------------------------------------
__global__ __launch_bounds__(256) void conv_kernel(
    const float* __restrict__ xz, const float* __restrict__ cw,
    const float* __restrict__ cb, float* __restrict__ xs)
{
  long gid = (long)blockIdx.x * 256 + threadIdx.x;
  if (gid >= (long)MR * DI_) return;
  int c = (int)(gid % DI_);
  long r = gid / DI_;
  int t = (int)(r & (TT - 1));
  float acc = cb[c];
  #pragma unroll
  for (int k = 0; k < 4; ++k) {
    int tt = t + k - 3;
    if (tt >= 0) acc = fmaf(cw[c * 4 + k], xz[(r + k - 3) * 1600 + c], acc);
  }
  xs[gid] = acc * sigf(acc);
}

// ---------------------------------------------------------------------------
// Selective scan v3.1: identical structure to v3, but ALL exponentials in the
// hot loop use raw v_exp_f32 (__builtin_amdgcn_exp2f) instead of libm exp2f.
// 4 channels/wave, 16 lanes/channel, 4 states/lane; pointer-bump addressing;
// 4-step unrolled groups, consume-then-prefetch; no LDS, no barriers.
// y = (scan_y + D*u) * silu(z) -> yout (stride 1600, dead xc cols of xz)
// ---------------------------------------------------------------------------
__global__ __launch_bounds__(256) void scan_kernel(
    const float* __restrict__ delta,   // [M,800]
    const float* __restrict__ dbc,     // [M,160] padded
    const float* __restrict__ xz,      // [M,1600]; z at +800
    const float* __restrict__ A_log,   // [800,64]
    const float* __restrict__ Dp,      // [800]
    const float* __restrict__ xs,      // [M,800] conv output u
    float* __restrict__ yout)          // [M,1600] strided; y at cols 0..799
{
  const int wid = blockIdx.x * 4 + (threadIdx.x >> 6);   // 0..3199
  const int lane = threadIdx.x & 63;
  const int b = wid / 200, cg = wid % 200;               // 200 waves/batch
  const int cl = lane >> 4, sq = lane & 15;              // channel-in-wave, state-quad
  const int c = cg * 4 + cl;
  const long rowbase = (long)b * TT;

  float a2[4], h[4] = {0.f, 0.f, 0.f, 0.f};
  {
    float4 al = *(const float4*)&A_log[c * 64 + sq * 4];
    a2[0] = -fexp2(al.x * LOG2E) * LOG2E;
    a2[1] = -fexp2(al.y * LOG2E) * LOG2E;
    a2[2] = -fexp2(al.z * LOG2E) * LOG2E;
    a2[3] = -fexp2(al.w * LOG2E) * LOG2E;
  }
  const float dcoef = Dp[c];

  const float* pB = dbc + rowbase * LDBC + 32 + sq * 4;
  const float* pC = dbc + rowbase * LDBC + 96 + sq * 4;
  const float* pD = delta + rowbase * DI_ + c;
  const float* pU = xs + rowbase * DI_ + c;
  const float* pZ = xz + rowbase * 1600 + 800 + c;
  float* pY = yout + rowbase * 1600 + c;

  float4 rB[4], rC[4];
  float rD[4], rU[4], rZ[4];
  #pragma unroll
  for (int s = 0; s < 4; ++s) {
    rB[s] = *(const float4*)(pB + s * LDBC);
    rC[s] = *(const float4*)(pC + s * LDBC);
    rD[s] = pD[s * DI_];
    rU[s] = pU[s * DI_];
    rZ[s] = pZ[s * 1600];
  }
  pB += 4 * LDBC; pC += 4 * LDBC; pD += 4 * DI_; pU += 4 * DI_; pZ += 4 * 1600;

  #define SCAN_STEP(s, PREFETCH)                                              \
    {                                                                         \
      const float dl = rD[s], u = rU[s], zz = rZ[s];                          \
      const float4 B4 = rB[s], C4 = rC[s];                                    \
      if (PREFETCH) {                                                         \
        rB[s] = *(const float4*)(pB + (s) * LDBC);                            \
        rC[s] = *(const float4*)(pC + (s) * LDBC);                            \
        rD[s] = pD[(s) * DI_];                                                \
        rU[s] = pU[(s) * DI_];                                                \
        rZ[s] = pZ[(s) * 1600];                                               \
      }                                                                       \
      const float du = dl * u;                                                \
      float y = 0.f, dA;                                                      \
      dA = fexp2(dl * a2[0]); h[0] = fmaf(dA, h[0], du * B4.x); y = fmaf(h[0], C4.x, y); \
      dA = fexp2(dl * a2[1]); h[1] = fmaf(dA, h[1], du * B4.y); y = fmaf(h[1], C4.y, y); \
      dA = fexp2(dl * a2[2]); h[2] = fmaf(dA, h[2], du * B4.z); y = fmaf(h[2], C4.z, y); \
      dA = fexp2(dl * a2[3]); h[3] = fmaf(dA, h[3], du * B4.w); y = fmaf(h[3], C4.w, y); \
      y += __shfl_xor(y, 1); y += __shfl_xor(y, 2);                           \
      y += __shfl_xor(y, 4); y += __shfl_xor(y, 8);                           \
      if (sq == 0) pY[(s) * 1600] = (y + dcoef * u) * (zz * sigfast(zz));     \
    }

  for (int g = 0; g < TT / 4 - 1; ++g) {
    SCAN_STEP(0, 1) SCAN_STEP(1, 1) SCAN_STEP(2, 1) SCAN_STEP(3, 1)
    pB += 4 * LDBC; pC += 4 * LDBC; pD += 4 * DI_; pU += 4 * DI_;
    pZ += 4 * 1600; pY += 4 * 1600;
  }
  SCAN_STEP(0, 0) SCAN_STEP(1, 0) SCAN_STEP(2, 0) SCAN_STEP(3, 0)
  #undef SCAN_STEP
}

// ---------------------------------------------------------------------------
// Fused double LayerNorm: out = LN2( LN1(x+m) + skip ), row width 400
// ---------------------------------------------------------------------------
__global__ __launch_bounds__(64) void ln2_kernel(
    const float* __restrict__ x, const float* __restrict__ m,
    const float* __restrict__ skip,
    const float* __restrict__ g1, const float* __restrict__ b1,
    const float* __restrict__ g2, const float* __restrict__ b2,
    float* __restrict__ out)
{
  const long row = blockIdx.x;
  const int lane = threadIdx.x;
  float v[7];
  float s = 0.f;
  #pragma unroll
  for (int i = 0; i < 7; ++i) {
    int cx = lane + i * 64;
    if (cx < HH) { v[i] = x[row * HH + cx] + m[row * HH + cx]; s += v[i]; }
    else v[i] = 0.f;
  }
  s = waveSum(s);
  float mu = s * (1.f / HH);
  float s2 = 0.f;
  #pragma unroll
  for (int i = 0; i < 7; ++i) {
    int cx = lane + i * 64;
    if (cx < HH) { float d = v[i] - mu; s2 += d * d; }
  }
  s2 = waveSum(s2);
  float rstd = rsqrtf(s2 * (1.f / HH) + 1e-5f);

  s = 0.f;
  #pragma unroll
  for (int i = 0; i < 7; ++i) {
    int cx = lane + i * 64;
    if (cx < HH) {
      v[i] = fmaf(g1[cx], (v[i] - mu) * rstd, b1[cx]) + skip[row * HH + cx];
      s += v[i];
    }
  }
  s = waveSum(s);
  float mu2 = s * (1.f / HH);
  s2 = 0.f;
  #pragma unroll
  for (int i = 0; i < 7; ++i) {
    int cx = lane + i * 64;
    if (cx < HH) { float d = v[i] - mu2; s2 += d * d; }
  }
  s2 = waveSum(s2);
  float rstd2 = rsqrtf(s2 * (1.f / HH) + 1e-5f);
  #pragma unroll
  for (int i = 0; i < 7; ++i) {
    int cx = lane + i * 64;
    if (cx < HH) out[row * HH + cx] = fmaf(g2[cx], (v[i] - mu2) * rstd2, b2[cx]);
  }
}

// ---------------------------------------------------------------------------
extern "C" void kernel_launch(void* const* d_in, const int* in_sizes, int n_in,
                              void* d_out, int out_size, void* d_ws, size_t ws_size,
                              hipStream_t stream) {
  const float* mag   = (const float*)d_in[0];
  const float* audio = (const float*)d_in[1];
  const float* video = (const float*)d_in[2];
  const float* apw = (const float*)d_in[3];
  const float* apb = (const float*)d_in[4];
  const float* vpw = (const float*)d_in[5];
  const float* vpb = (const float*)d_in[6];
  const float* fgw = (const float*)d_in[7];
  const float* fgb = (const float*)d_in[8];
  const float* fbw = (const float*)d_in[9];
  const float* fbb = (const float*)d_in[10];
  const float* ipw = (const float*)d_in[11];
  const float* cw  = (const float*)d_in[12];
  const float* cb  = (const float*)d_in[13];
  const float* xpw = (const float*)d_in[14];
  const float* dtw = (const float*)d_in[15];
  const float* dtb = (const float*)d_in[16];
  const float* alog= (const float*)d_in[17];
  const float* dd  = (const float*)d_in[18];
  const float* opw = (const float*)d_in[19];
  const float* mng = (const float*)d_in[20];
  const float* mnb = (const float*)d_in[21];
  const float* spw = (const float*)d_in[22];
  const float* spb = (const float*)d_in[23];
  const float* fng = (const float*)d_in[24];
  const float* fnb = (const float*)d_in[25];
  const float* fc1w= (const float*)d_in[26];
  const float* fc1b= (const float*)d_in[27];
  const float* fc2w= (const float*)d_in[28];
  const float* fc2b= (const float*)d_in[29];
  const float* fc3w= (const float*)d_in[30];
  const float* fc3b= (const float*)d_in[31];
  const float* mmw = (const float*)d_in[32];
  const float* mmb = (const float*)d_in[33];
  float* outp = (float*)d_out;

  float* w = (float*)d_ws;
  const long M = MR;
  float* av   = w;              // [M,400] audio_vec; later m
  float* vv   = w + M * 400;    // [M,400] video_vec
  float* gam  = w + M * 800;    // [M,400] gamma (dead after FiLM)
  float* dbcb = w + M * 800;    // [M,160] padded dbc (reuses gam)
  float* xbuf = w + M * 1200;   // [M,400] x
  float* skip = w + M * 1600;   // [M,400]
  float* xzb  = w + M * 2000;   // [M,1600] xz; y into cols 0..799; later h1,h2
  float* h1   = w + M * 2000;   // [M,600]
  float* h2   = w + M * 2600;   // [M,600]
  float* xsb  = w + M * 3600;   // [M,800] conv u; later mout
  float* mout = w + M * 3600;   // [M,400]
  float* delt = w + M * 4400;   // [M,800] delta; later h3
  float* h3   = w + M * 4400;   // [M,600]
  unsigned short* wt = (unsigned short*)(w + M * 5200);  // bf16 weights arena
  // high-water ~350.6 MB

  // transposed bf16 weights: [Npad][Kt]
  unsigned short* apT = wt;                 // 448 x 2080
  unsigned short* spT = apT + 448 * 2080;
  unsigned short* vpT = spT + 448 * 2080;   // 448 x 512
  unsigned short* fgT = vpT + 448 * 512;    // 448 x 416
  unsigned short* fbT = fgT + 448 * 416;
  unsigned short* ipT = fbT + 448 * 416;    // 1600 x 416
  unsigned short* xpT = ipT + 1600 * 416;   // 192 x 800
  unsigned short* opT = xpT + 192 * 800;    // 448 x 800
  unsigned short* f1T = opT + 448 * 800;    // 640 x 416
  unsigned short* f2T = f1T + 640 * 416;    // 640 x 608
  unsigned short* f3T = f2T + 640 * 608;
  unsigned short* mmT = f3T + 640 * 608;    // 320 x 608

  const dim3 blk(256);

  // weight transposes (bf16, zero-padded)
  wtrans<<<dim3(65, 14), blk, 0, stream>>>(apw, 2056, 400, apT, 2080, 448);
  wtrans<<<dim3(65, 14), blk, 0, stream>>>(spw, 2056, 400, spT, 2080, 448);
  wtrans<<<dim3(16, 14), blk, 0, stream>>>(vpw, 512, 400, vpT, 512, 448);
  wtrans<<<dim3(13, 14), blk, 0, stream>>>(fgw, 400, 400, fgT, 416, 448);
  wtrans<<<dim3(13, 14), blk, 0, stream>>>(fbw, 400, 400, fbT, 416, 448);
  wtrans<<<dim3(13, 50), blk, 0, stream>>>(ipw, 400, 1600, ipT, 416, 1600);
  wtrans<<<dim3(25, 6),  blk, 0, stream>>>(xpw, 800, 153, xpT, 800, 192);
  wtrans<<<dim3(25, 14), blk, 0, stream>>>(opw, 800, 400, opT, 800, 448);
  wtrans<<<dim3(13, 20), blk, 0, stream>>>(fc1w, 400, 600, f1T, 416, 640);
  wtrans<<<dim3(19, 20), blk, 0, stream>>>(fc2w, 600, 600, f2T, 608, 640);
  wtrans<<<dim3(19, 20), blk, 0, stream>>>(fc3w, 600, 600, f3T, 608, 640);
  wtrans<<<dim3(19, 10), blk, 0, stream>>>(mmw, 600, 257, mmT, 608, 320);

  const int gy = MR / 128;  // 128

  // audio_vec / video_vec / skip
  mgemm<0><<<dim3(7, gy), blk, 0, stream>>>(audio, 2056, apT, 2080, apb, av, 400, nullptr, 0, nullptr, 0, 400, 2056, 0);
  mgemm<0><<<dim3(7, gy), blk, 0, stream>>>(video, 512, vpT, 512, vpb, vv, 400, nullptr, 0, nullptr, 0, 400, 512, 0);
  mgemm<0><<<dim3(7, gy), blk, 0, stream>>>(audio, 2056, spT, 2080, spb, skip, 400, nullptr, 0, nullptr, 0, 400, 2056, 0);
  // gamma; then x = av*gamma + (beta + bias)
  mgemm<0><<<dim3(7, gy), blk, 0, stream>>>(vv, 400, fgT, 416, fgb, gam, 400, nullptr, 0, nullptr, 0, 400, 400, 0);
  mgemm<4><<<dim3(7, gy), blk, 0, stream>>>(vv, 400, fbT, 416, fbb, xbuf, 400, av, 400, gam, 400, 400, 400, 0);
  // xz = x @ in_proj_w
  mgemm<0><<<dim3(25, gy), blk, 0, stream>>>(xbuf, 400, ipT, 416, nullptr, xzb, 1600, nullptr, 0, nullptr, 0, 1600, 400, 0);
  // conv + silu -> xs
  conv_kernel<<<dim3((MR * DI_) / 256), blk, 0, stream>>>(xzb, cw, cb, xsb);
  // dbc = xs @ x_proj_w  (padded/remapped into ld=160)
  mgemm<0><<<dim3(3, gy), blk, 0, stream>>>(xsb, 800, xpT, 800, nullptr, dbcb, LDBC, nullptr, 0, nullptr, 0, 153, 800, 1);
  // delta = softplus(dt @ dt_proj_w + b)  [fp32, K=25]
  gemm_kernel<3><<<dim3(13, MR / 64), blk, 0, stream>>>(dbcb, LDBC, dtw, 800, dtb, delt, 800, 800, 25);
  // selective scan -> y into xzb cols 0..799 (stride 1600)
  scan_kernel<<<dim3(800), blk, 0, stream>>>(delt, dbcb, xzb, alog, dd, xsb, xzb);
  // m = y @ out_proj_w -> av
  mgemm<0><<<dim3(7, gy), blk, 0, stream>>>(xzb, 1600, opT, 800, nullptr, av, 400, nullptr, 0, nullptr, 0, 400, 800, 0);
  // mamba_out = LN2(LN1(x+m)+skip) -> mout
  ln2_kernel<<<dim3(MR), dim3(64), 0, stream>>>(xbuf, av, skip, mng, mnb, fng, fnb, mout);
  // MLP
  mgemm<1><<<dim3(10, gy), blk, 0, stream>>>(mout, 400, f1T, 416, fc1b, h1, 600, nullptr, 0, nullptr, 0, 600, 400, 0);
  mgemm<1><<<dim3(10, gy), blk, 0, stream>>>(h1, 600, f2T, 608, fc2b, h2, 600, nullptr, 0, nullptr, 0, 600, 600, 0);
  mgemm<1><<<dim3(10, gy), blk, 0, stream>>>(h2, 600, f3T, 608, fc3b, h3, 600, nullptr, 0, nullptr, 0, 600, 600, 0);
  // mask = sigmoid(h3 @ mmw + b) * mag -> out
  mgemm<2><<<dim3(5, gy), blk, 0, stream>>>(h3, 600, mmT, 608, mmb, outp, 257, mag, 257, nullptr, 0, 257, 600, 0);
}